// Round 1
// 367.014 us; speedup vs baseline: 1.3756x; 1.3756x over previous
//
#include <hip/hip_runtime.h>
#include <hip/hip_bf16.h>

typedef unsigned short u16;
typedef __attribute__((ext_vector_type(8))) short s8v;
typedef __attribute__((ext_vector_type(4))) short s4v;
typedef __attribute__((ext_vector_type(4))) float f4v;

__device__ __forceinline__ float s2f(u16 s) {
    unsigned int u = ((unsigned int)s) << 16;
    return __builtin_bit_cast(float, u);
}
__device__ __forceinline__ u16 f2s(float f) {
    __hip_bfloat16 h = __float2bfloat16(f);
    return __builtin_bit_cast(u16, h);
}

// async global->LDS DMA, 16 B per lane; LDS dst must be lane-linear
__device__ __forceinline__ void gl2lds16(const u16* g, u16* l) {
    __builtin_amdgcn_global_load_lds((const __attribute__((address_space(1))) void*)g,
                                     (__attribute__((address_space(3))) void*)l, 16, 0, 0);
}

#define BSZ 4
#define DM 1024
#define QLEN 512
#define MLEN 512
#define KLEN 1024
#define DI 4096
#define NH 16
#define DH 64
#define WIN 256   // valid keys: j = i+257 .. i+512

// ---- f32 -> bf16 weight conversion ----
__global__ __launch_bounds__(256) void conv_w(const float* __restrict__ src,
                                              u16* __restrict__ dst, int n4) {
    int i = blockIdx.x * 256 + threadIdx.x;
    if (i < n4) {
        f4v v = *(const f4v*)&src[(size_t)i * 4];
        s4v o;
#pragma unroll
        for (int k = 0; k < 4; ++k) o[k] = (short)f2s(v[k]);
        *(s4v*)&dst[(size_t)i * 4] = o;
    }
}

// ---- transpose f32 (feature-major) -> bf16 (position-major) ----
__global__ __launch_bounds__(256) void trans_f2b(
    const float* __restrict__ src, long sS, int ldS, int colOff,
    u16* __restrict__ dst, long sD, int ldD, int rowOff)
{
    __shared__ float tile[32][33];
    int b = blockIdx.z;
    int t0 = blockIdx.x * 32, f0 = blockIdx.y * 32;
    int tx = threadIdx.x, ty = threadIdx.y;   // (32, 8)
#pragma unroll
    for (int p = 0; p < 4; ++p)
        tile[ty + 8 * p][tx] = src[(size_t)b * sS + (size_t)(f0 + ty + 8 * p) * ldS + colOff + t0 + tx];
    __syncthreads();
#pragma unroll
    for (int p = 0; p < 4; ++p)
        dst[(size_t)b * sD + (size_t)(rowOff + t0 + ty + 8 * p) * ldD + f0 + tx] = f2s(tile[tx][ty + 8 * p]);
}

// ---- transpose bf16 (position-major) -> f32 (feature-major) ----
__global__ __launch_bounds__(256) void trans_b2f(
    const u16* __restrict__ src, long sS, int ldS,
    float* __restrict__ dst, long sD, int ldD)
{
    __shared__ float tile[32][33];
    int b = blockIdx.z;
    int t0 = blockIdx.x * 32, f0 = blockIdx.y * 32;
    int tx = threadIdx.x, ty = threadIdx.y;
#pragma unroll
    for (int p = 0; p < 4; ++p)
        tile[ty + 8 * p][tx] = s2f(src[(size_t)b * sS + (size_t)(f0 + ty + 8 * p) * ldS + t0 + tx]);
    __syncthreads();
#pragma unroll
    for (int p = 0; p < 4; ++p)
        dst[(size_t)b * sD + (size_t)(t0 + ty + 8 * p) * ldD + f0 + tx] = tile[tx][ty + 8 * p];
}

// ---- MFMA GEMM (m97-style): C^T(N x M) = A(M x K, bf16) @ B^T(N x K, bf16) ----
// SPLIT>1: each z writes a PRIVATE f32 partial buffer at fOut + z*pstride (no atomics);
//          the consumer (ln_f) sums the partials.
template<int BN, int SPLIT>
__global__ __launch_bounds__(256) void gemm_bt(
    const u16* __restrict__ A,
    const u16* __restrict__ B,
    u16* __restrict__ C,
    float* __restrict__ fOut,
    int M, int K,
    const float* __restrict__ bias,
    const float* __restrict__ uss,   // f32 [b][3072][1024], n = b*1024 + t
    int relu,
    long pstride)                    // f32-element stride between split partials (may be negative)
{
    constexpr int BM = 128, BK = 64;
    constexpr int MI = (BN == 128) ? 4 : 2;
    constexpr int NI = 4;
    const int n0 = blockIdx.x * BN, m0 = blockIdx.y * BM;
    const int Ks = K / SPLIT;
    const int kbeg = blockIdx.z * Ks;
    __shared__ __align__(16) u16 As[BM * BK];
    __shared__ __align__(16) u16 Bs[BN * BK];
    const int tid = threadIdx.x, lane = tid & 63, wv = tid >> 6;
    const int l15 = lane & 15, quad = lane >> 4;
    const int wm = (BN == 128) ? (wv >> 1) * 64 : wv * 32;
    const int wn = (BN == 128) ? (wv & 1) * 64 : 0;
    f4v acc[MI][NI] = {};
    for (int kk = kbeg; kk < kbeg + Ks; kk += BK) {
        __syncthreads();
#pragma unroll
        for (int p = 0; p < (BM * 8) / 256; ++p) {
            int c = p * 256 + tid, r = c >> 3, q = c & 7, qs = q ^ (r & 7);
            gl2lds16(&A[(size_t)(m0 + r) * K + kk + qs * 8], &As[c * 8]);
        }
#pragma unroll
        for (int p = 0; p < (BN * 8) / 256; ++p) {
            int c = p * 256 + tid, r = c >> 3, q = c & 7, qs = q ^ (r & 7);
            gl2lds16(&B[(size_t)(n0 + r) * K + kk + qs * 8], &Bs[c * 8]);
        }
        __syncthreads();
#pragma unroll
        for (int k0 = 0; k0 < BK; k0 += 32) {
            s8v af[MI], bf[NI];
#pragma unroll
            for (int mi = 0; mi < MI; ++mi) {
                int r = wm + mi * 16 + l15;
                af[mi] = *(const s8v*)&As[r * BK + ((((k0 >> 3) + quad) ^ (r & 7)) << 3)];
            }
#pragma unroll
            for (int ni = 0; ni < NI; ++ni) {
                int r = wn + ni * 16 + l15;
                bf[ni] = *(const s8v*)&Bs[r * BK + ((((k0 >> 3) + quad) ^ (r & 7)) << 3)];
            }
#pragma unroll
            for (int mi = 0; mi < MI; ++mi)
#pragma unroll
                for (int ni = 0; ni < NI; ++ni)
                    acc[mi][ni] = __builtin_amdgcn_mfma_f32_16x16x32_bf16(af[mi], bf[ni], acc[mi][ni], 0, 0, 0);
        }
    }
    if (SPLIT > 1) {
        float* base = fOut + (long)blockIdx.z * pstride;
#pragma unroll
        for (int mi = 0; mi < MI; ++mi) {
            int m = m0 + wm + mi * 16 + quad * 4;
#pragma unroll
            for (int ni = 0; ni < NI; ++ni) {
                int n = n0 + wn + ni * 16 + l15;
                *(f4v*)&base[(size_t)n * M + m] = acc[mi][ni];   // plain 16B store, no RMW
            }
        }
    } else {
#pragma unroll
        for (int mi = 0; mi < MI; ++mi) {
            int m = m0 + wm + mi * 16 + quad * 4;
            float bv[4] = {0.f, 0.f, 0.f, 0.f};
            if (bias) {
#pragma unroll
                for (int r2 = 0; r2 < 4; ++r2) bv[r2] = bias[m + r2];
            }
#pragma unroll
            for (int ni = 0; ni < NI; ++ni) {
                int n = n0 + wn + ni * 16 + l15;
                float o[4];
#pragma unroll
                for (int r2 = 0; r2 < 4; ++r2) o[r2] = acc[mi][ni][r2] + bv[r2];
                if (uss) {
                    int b = n >> 10, t = n & 1023;
#pragma unroll
                    for (int r2 = 0; r2 < 4; ++r2)
                        o[r2] += uss[((size_t)b * 3072 + m + r2) * 1024 + t];
                }
                if (relu) {
#pragma unroll
                    for (int r2 = 0; r2 < 4; ++r2) o[r2] = fmaxf(o[r2], 0.f);
                }
                s4v st;
#pragma unroll
                for (int r2 = 0; r2 < 4; ++r2) st[r2] = (short)f2s(o[r2]);
                *(s4v*)&C[(size_t)n * M + m] = st;
            }
        }
    }
}

// ---- MFMA banded flash attention ----
// block = (qtile of 16, head n, batch b); 256 thr = 4 waves.
// Keys for tile: j = j0 .. j0+271 (j0 = i0+257), c = j - j0; band: c - qi in [0,255].
// BD handled by scattering RQ[qi][t'] into S[qi][qi+t'] over an S pre-init of -1e30.
#define QT 16
#define KT 272    // 17 tiles of 16
#define KROW 72   // K LDS row stride (u16): 2-way banks
#define VROW 280  // V^T LDS row stride (u16): 2-way banks
#define SROW 272  // S row stride (f32)
#define PROW 280  // P row stride (u16)
__global__ __launch_bounds__(256) void attn_mfma(
    const u16* __restrict__ WHT,      // (BSZ, KLEN, 3*DM) bf16
    const u16* __restrict__ RT,       // (WIN, DM) bf16
    const float* __restrict__ rwb, const float* __restrict__ rrb,
    u16* __restrict__ avT)            // (BSZ, QLEN, DM) bf16
{
    __shared__ __align__(16) u16  sKV[KT * KROW];   // 39168 B; phase2 holds V^T [64][VROW]
    __shared__ __align__(16) float sS[QT * SROW];   // 17408 B
    __shared__ __align__(16) u16  sP[QT * PROW];    //  8960 B   (total = 65536 B exactly)

    const int qt = blockIdx.x, n = blockIdx.y, b = blockIdx.z;
    const int i0 = qt * QT, j0 = i0 + WIN + 1;
    const int tid = threadIdx.x, lane = tid & 63, wv = tid >> 6;
    const int l15 = lane & 15, quad = lane >> 4;
    const u16* W = WHT + (size_t)b * KLEN * (3 * DM);

    // Q fragments (A-operand rows = l15 = qi), biases baked in
    s8v qac[2], qbd[2];
    {
        int qrow = MLEN + i0 + l15;
#pragma unroll
        for (int kc = 0; kc < 2; ++kc) {
            int col = n * DH + kc * 32 + quad * 8;
            s8v qv = *(const s8v*)&W[(size_t)qrow * (3 * DM) + col];
            s8v a, c;
#pragma unroll
            for (int e = 0; e < 8; ++e) {
                float qf = s2f((u16)qv[e]);
                a[e] = (short)f2s(qf + rwb[col + e]);
                c[e] = (short)f2s(qf + rrb[col + e]);
            }
            qac[kc] = a; qbd[kc] = c;
        }
    }

    // stage K tile: row c, 8 chunks of 8 u16; j clamped (garbage lands only in masked cells)
    for (int t = tid; t < KT * 8; t += 256) {
        int r = t >> 3, q = t & 7;
        int j = j0 + r; if (j > KLEN - 1) j = KLEN - 1;
        *(s8v*)&sKV[r * KROW + q * 8] = *(const s8v*)&W[(size_t)j * (3 * DM) + DM + n * DH + q * 8];
    }
    // init S to -1e30 (mask default)
    for (int t = tid; t < QT * SROW; t += 256) sS[t] = -1e30f;
    __syncthreads();

    // RQ = rr_q @ R^T, scattered into S at [qi][qi + t']  (4 ci' tiles per wave)
#pragma unroll
    for (int cc = 0; cc < 4; ++cc) {
        int ci = wv + cc * 4;
        f4v acc = {};
#pragma unroll
        for (int kc = 0; kc < 2; ++kc) {
            s8v bf = *(const s8v*)&RT[(size_t)(ci * 16 + l15) * DM + n * DH + kc * 32 + quad * 8];
            acc = __builtin_amdgcn_mfma_f32_16x16x32_bf16(qbd[kc], bf, acc, 0, 0, 0);
        }
#pragma unroll
        for (int r2 = 0; r2 < 4; ++r2) {
            int qi = quad * 4 + r2;
            sS[qi * SROW + qi + ci * 16 + l15] = acc[r2];
        }
    }
    __syncthreads();

    // S += Q·K^T  (ci tiles round-robin over waves)
    for (int ci = wv; ci < 17; ci += 4) {
        f4v acc = {};
#pragma unroll
        for (int kc = 0; kc < 2; ++kc) {
            s8v bf = *(const s8v*)&sKV[(ci * 16 + l15) * KROW + kc * 32 + quad * 8];
            acc = __builtin_amdgcn_mfma_f32_16x16x32_bf16(qac[kc], bf, acc, 0, 0, 0);
        }
#pragma unroll
        for (int r2 = 0; r2 < 4; ++r2) {
            int qi = quad * 4 + r2;
            sS[qi * SROW + ci * 16 + l15] += acc[r2];
        }
    }
    __syncthreads();

    // stage V^T into sKV as [d][VROW]: thread group q=tid>>5 owns d-chunk, r fast for bank spread
    {
        int q = tid >> 5, r0 = tid & 31;
        for (int k = 0; k < 9; ++k) {
            int r = r0 + 32 * k;
            if (r < KT) {
                int j = j0 + r; if (j > KLEN - 1) j = KLEN - 1;
                s8v vv = *(const s8v*)&W[(size_t)j * (3 * DM) + 2 * DM + n * DH + q * 8];
#pragma unroll
                for (int e = 0; e < 8; ++e)
                    sKV[(q * 8 + e) * VROW + r] = (u16)vv[e];
            }
        }
    }

    // softmax: 16 groups of 16 lanes, group g owns row g
    {
        int g = tid >> 4, l = tid & 15;
        float vals[17], mx = -1e30f;
#pragma unroll
        for (int k = 0; k < 17; ++k) {
            float s = sS[g * SROW + l + 16 * k] * 0.125f;
            vals[k] = s; mx = fmaxf(mx, s);
        }
#pragma unroll
        for (int d = 1; d < 16; d <<= 1) mx = fmaxf(mx, __shfl_xor(mx, d, 16));
        float sum = 0.f;
#pragma unroll
        for (int k = 0; k < 17; ++k) { vals[k] = __expf(vals[k] - mx); sum += vals[k]; }
#pragma unroll
        for (int d = 1; d < 16; d <<= 1) sum += __shfl_xor(sum, d, 16);
        float inv = 1.f / sum;
#pragma unroll
        for (int k = 0; k < 17; ++k) sP[g * PROW + l + 16 * k] = f2s(vals[k] * inv);
    }
    __syncthreads();

    // O = P @ V : wave wv owns d-tile ni=wv; k = 272 -> 8 full chunks + 16-wide tail
    f4v o = {};
    for (int kc = 0; kc < 9; ++kc) {
        s8v a = {}, bb = {};
        if (kc < 8) {
            a  = *(const s8v*)&sP[l15 * PROW + kc * 32 + quad * 8];
            bb = *(const s8v*)&sKV[(wv * 16 + l15) * VROW + kc * 32 + quad * 8];
        } else if (quad < 2) {
            a  = *(const s8v*)&sP[l15 * PROW + 256 + quad * 8];
            bb = *(const s8v*)&sKV[(wv * 16 + l15) * VROW + 256 + quad * 8];
        }
        o = __builtin_amdgcn_mfma_f32_16x16x32_bf16(a, bb, o, 0, 0, 0);
    }
#pragma unroll
    for (int r2 = 0; r2 < 4; ++r2) {
        int qi = quad * 4 + r2;
        avT[((size_t)b * QLEN + i0 + qi) * DM + n * DH + wv * 16 + l15] = f2s(o[r2]);
    }
}

// ---- layernorm: out = LN(sum of nparts partials + bias + res_bf16), row-contiguous ----
__global__ __launch_bounds__(256) void ln_f(
    const float* __restrict__ P, long pstride, int nparts,
    const float* __restrict__ bias,
    const u16* __restrict__ res, int resMode, u16* __restrict__ out)
{
    int n = blockIdx.x, tid = threadIdx.x;
    int lane = tid & 63, wv = tid >> 6;
    int f = tid * 4;
    int rrow = resMode ? (((n >> 9) * 2 + 1) * 512 + (n & 511)) : n;
    f4v pv = *(const f4v*)&P[(size_t)n * DM + f];
    for (int p = 1; p < nparts; ++p) {
        const float* Pp = P + (long)p * pstride;
        pv += *(const f4v*)&Pp[(size_t)n * DM + f];
    }
    s4v rv = *(const s4v*)&res[(size_t)rrow * DM + f];
    f4v bv = *(const f4v*)&bias[f];
    float v[4];
#pragma unroll
    for (int k = 0; k < 4; ++k) v[k] = pv[k] + bv[k] + s2f((u16)rv[k]);
    float s = v[0] + v[1] + v[2] + v[3];
    float ss = v[0] * v[0] + v[1] * v[1] + v[2] * v[2] + v[3] * v[3];
#pragma unroll
    for (int d = 1; d < 64; d <<= 1) {
        s += __shfl_xor(s, d, 64);
        ss += __shfl_xor(ss, d, 64);
    }
    __shared__ float ps[4], pss[4];
    if (lane == 0) { ps[wv] = s; pss[wv] = ss; }
    __syncthreads();
    float S = ps[0] + ps[1] + ps[2] + ps[3];
    float SS = pss[0] + pss[1] + pss[2] + pss[3];
    float m = S * (1.f / DM);
    float var = SS * (1.f / DM) - m * m;
    float inv = rsqrtf(fmaxf(var, 0.f) + 1e-5f);
    s4v st;
#pragma unroll
    for (int k = 0; k < 4; ++k) st[k] = (short)f2s((v[k] - m) * inv);
    *(s4v*)&out[(size_t)n * DM + f] = st;
}

extern "C" void kernel_launch(void* const* d_in, const int* in_sizes, int n_in,
                              void* d_out, int out_size, void* d_ws, size_t ws_size,
                              hipStream_t stream) {
    const float* z1ss  = (const float*)d_in[0];
    const float* uss   = (const float*)d_in[1];
    const float* z0    = (const float*)d_in[2];
    const float* pos   = (const float*)d_in[3];
    const float* qkv_w = (const float*)d_in[4];
    const float* r_w   = (const float*)d_in[5];
    const float* rwb   = (const float*)d_in[6];
    const float* rrb   = (const float*)d_in[7];
    const float* o_w   = (const float*)d_in[8];
    const float* o_b   = (const float*)d_in[9];
    const float* ff1_w = (const float*)d_in[10];
    const float* ff1_b = (const float*)d_in[11];
    const float* ff2_w = (const float*)d_in[12];
    const float* ff2_b = (const float*)d_in[13];

    u16* ws = (u16*)d_ws;
    u16* wQ   = ws;             // 3072x1024
    u16* wR   = ws + 3145728;
    u16* wO   = ws + 4194304;
    u16* wF1  = ws + 5242880;
    u16* wF2  = ws + 9437184;
    u16* catT = ws + 13631488;  // (4,1024,1024); later aliased as outT
    u16* whT  = ws + 17825792;  // (4,1024,3072); later aliased as hT
    u16* posT = ws + 30408704;  // (256,1024)
    u16* rT   = ws + 30670848;  // (256,1024)
    u16* avT  = ws + 30932992;  // (2048,1024)
    u16* xT   = ws + 33030144;  // (2048,1024)
    float* pref = (float*)(ws + 35127296);  // 2048x1024 f32  (split partial 0)
    u16* hT   = whT;
    u16* outT = catT;

    // split partial 1: workspace offset 0 = wQ+wR region (exactly 8 MB), dead by the
    // time o-proj / ff2 run (qkv + r gemms already consumed those weights).
    float* part1 = (float*)d_ws;
    long pstr = part1 - pref;   // negative f32-element stride between partials

    dim3 tblk(32, 8);

    conv_w<<<3072, 256, 0, stream>>>(qkv_w, wQ, 786432);
    conv_w<<<1024, 256, 0, stream>>>(r_w,   wR, 262144);
    conv_w<<<1024, 256, 0, stream>>>(o_w,   wO, 262144);
    conv_w<<<4096, 256, 0, stream>>>(ff1_w, wF1, 1048576);
    conv_w<<<4096, 256, 0, stream>>>(ff2_w, wF2, 1048576);

    trans_f2b<<<dim3(16, 32, BSZ), tblk, 0, stream>>>(z0, (long)DM * MLEN, MLEN, 0,
                                                      catT, (long)KLEN * DM, DM, 0);
    trans_f2b<<<dim3(16, 32, BSZ), tblk, 0, stream>>>(z1ss, (long)DM * QLEN, QLEN, 0,
                                                      catT, (long)KLEN * DM, DM, MLEN);
    trans_f2b<<<dim3(8, 32, 1), tblk, 0, stream>>>(pos, 0, KLEN, KLEN - WIN,
                                                   posT, 0, DM, 0);

    // qkv: whT(4096 x 3072) = (qkv_w @ cat)^T + uss^T
    gemm_bt<128, 1><<<dim3(32, 24, 1), 256, 0, stream>>>(
        wQ, catT, whT, nullptr, 3 * DM, DM, nullptr, uss, 0, 0);

    // r: rT(256 x 1024) = (r_w @ pos[:,768:])^T
    gemm_bt<64, 1><<<dim3(4, 8, 1), 256, 0, stream>>>(
        wR, posT, rT, nullptr, DM, DM, nullptr, nullptr, 0, 0);

    // MFMA banded attention -> avT
    attn_mfma<<<dim3(QLEN / QT, NH, BSZ), 256, 0, stream>>>(whT, rT, rwb, rrb, avT);

    // o-proj split-2, private partials (no atomics, no memset)
    gemm_bt<64, 2><<<dim3(32, 8, 2), 256, 0, stream>>>(
        wO, avT, nullptr, pref, DM, DM, nullptr, nullptr, 0, pstr);

    ln_f<<<2048, 256, 0, stream>>>(pref, pstr, 2, o_b, catT, 1, xT);

    // ff1
    gemm_bt<128, 1><<<dim3(16, 32, 1), 256, 0, stream>>>(
        wF1, xT, hT, nullptr, DI, DM, ff1_b, nullptr, 1, 0);

    // ff2 split-2, private partials (no atomics, no memset)
    gemm_bt<64, 2><<<dim3(32, 8, 2), 256, 0, stream>>>(
        wF2, hT, nullptr, pref, DM, DI, nullptr, nullptr, 0, pstr);

    ln_f<<<2048, 256, 0, stream>>>(pref, pstr, 2, ff2_b, xT, 0, outT);

    trans_b2f<<<dim3(32, 16, BSZ), tblk, 0, stream>>>(outT, (long)QLEN * DM, DM,
                                                      (float*)d_out, (long)DM * QLEN, QLEN);
}

// Round 2
// 365.119 us; speedup vs baseline: 1.3827x; 1.0052x over previous
//
#include <hip/hip_runtime.h>
#include <hip/hip_bf16.h>

typedef unsigned short u16;
typedef __attribute__((ext_vector_type(8))) short s8v;
typedef __attribute__((ext_vector_type(4))) short s4v;
typedef __attribute__((ext_vector_type(4))) float f4v;

__device__ __forceinline__ float s2f(u16 s) {
    unsigned int u = ((unsigned int)s) << 16;
    return __builtin_bit_cast(float, u);
}
__device__ __forceinline__ u16 f2s(float f) {
    __hip_bfloat16 h = __float2bfloat16(f);
    return __builtin_bit_cast(u16, h);
}

// async global->LDS DMA, 16 B per lane; LDS dst must be lane-linear
__device__ __forceinline__ void gl2lds16(const u16* g, u16* l) {
    __builtin_amdgcn_global_load_lds((const __attribute__((address_space(1))) void*)g,
                                     (__attribute__((address_space(3))) void*)l, 16, 0, 0);
}

#define BSZ 4
#define DM 1024
#define QLEN 512
#define MLEN 512
#define KLEN 1024
#define DI 4096
#define NH 16
#define DH 64
#define WIN 256   // valid keys: j = i+257 .. i+512

// ---- merged f32 -> bf16 weight conversion (5 tensors, 1 launch) ----
__global__ __launch_bounds__(256) void conv_w5(
    const float* __restrict__ s0, const float* __restrict__ s1,
    const float* __restrict__ s2, const float* __restrict__ s3,
    const float* __restrict__ s4,
    u16* __restrict__ d0, u16* __restrict__ d1, u16* __restrict__ d2,
    u16* __restrict__ d3, u16* __restrict__ d4)
{
    const int e0 = 786432, e1 = e0 + 262144, e2 = e1 + 262144,
              e3 = e2 + 1048576, e4 = e3 + 1048576;
    int i = blockIdx.x * 256 + threadIdx.x;
    const float* s; u16* d; int off;
    if (i < e0)      { s = s0; d = d0; off = i; }
    else if (i < e1) { s = s1; d = d1; off = i - e0; }
    else if (i < e2) { s = s2; d = d2; off = i - e1; }
    else if (i < e3) { s = s3; d = d3; off = i - e2; }
    else if (i < e4) { s = s4; d = d4; off = i - e3; }
    else return;
    f4v v = *(const f4v*)&s[(size_t)off * 4];
    s4v o;
#pragma unroll
    for (int k = 0; k < 4; ++k) o[k] = (short)f2s(v[k]);
    *(s4v*)&d[(size_t)off * 4] = o;
}

// ---- transpose f32 (feature-major) -> bf16 (position-major) ----
__global__ __launch_bounds__(256) void trans_f2b(
    const float* __restrict__ src, long sS, int ldS, int colOff,
    u16* __restrict__ dst, long sD, int ldD, int rowOff)
{
    __shared__ float tile[32][33];
    int b = blockIdx.z;
    int t0 = blockIdx.x * 32, f0 = blockIdx.y * 32;
    int tx = threadIdx.x, ty = threadIdx.y;   // (32, 8)
#pragma unroll
    for (int p = 0; p < 4; ++p)
        tile[ty + 8 * p][tx] = src[(size_t)b * sS + (size_t)(f0 + ty + 8 * p) * ldS + colOff + t0 + tx];
    __syncthreads();
#pragma unroll
    for (int p = 0; p < 4; ++p)
        dst[(size_t)b * sD + (size_t)(rowOff + t0 + ty + 8 * p) * ldD + f0 + tx] = f2s(tile[tx][ty + 8 * p]);
}

// ---- transpose-add: dst(bf16, [b][1024][3072]) += src(f32, [b][3072][1024])^T ----
__global__ __launch_bounds__(256) void trans_add(
    const float* __restrict__ src, u16* __restrict__ dst)
{
    __shared__ float tile[32][33];
    int b = blockIdx.z;
    int t0 = blockIdx.x * 32, f0 = blockIdx.y * 32;
    int tx = threadIdx.x, ty = threadIdx.y;   // (32, 8)
    const float* S = src + (size_t)b * 3072 * 1024;
    u16* D = dst + (size_t)b * 1024 * 3072;
#pragma unroll
    for (int p = 0; p < 4; ++p)
        tile[ty + 8 * p][tx] = S[(size_t)(f0 + ty + 8 * p) * 1024 + t0 + tx];
    __syncthreads();
#pragma unroll
    for (int p = 0; p < 4; ++p) {
        size_t o = (size_t)(t0 + ty + 8 * p) * 3072 + f0 + tx;
        D[o] = f2s(s2f(D[o]) + tile[tx][ty + 8 * p]);
    }
}

// ---- transpose bf16 (position-major) -> f32 (feature-major) ----
__global__ __launch_bounds__(256) void trans_b2f(
    const u16* __restrict__ src, long sS, int ldS,
    float* __restrict__ dst, long sD, int ldD)
{
    __shared__ float tile[32][33];
    int b = blockIdx.z;
    int t0 = blockIdx.x * 32, f0 = blockIdx.y * 32;
    int tx = threadIdx.x, ty = threadIdx.y;
#pragma unroll
    for (int p = 0; p < 4; ++p)
        tile[ty + 8 * p][tx] = s2f(src[(size_t)b * sS + (size_t)(f0 + ty + 8 * p) * ldS + t0 + tx]);
    __syncthreads();
#pragma unroll
    for (int p = 0; p < 4; ++p)
        dst[(size_t)b * sD + (size_t)(t0 + ty + 8 * p) * ldD + f0 + tx] = tile[tx][ty + 8 * p];
}

// ---- MFMA GEMM (m97-style): C^T(N x M) = A(M x K, bf16) @ B^T(N x K, bf16) ----
// SPLIT>1: each z writes a PRIVATE f32 partial buffer at fOut + z*pstride (no atomics);
//          the consumer (ln_f) sums the partials.
template<int BN, int SPLIT>
__global__ __launch_bounds__(256) void gemm_bt(
    const u16* __restrict__ A,
    const u16* __restrict__ B,
    u16* __restrict__ C,
    float* __restrict__ fOut,
    int M, int K,
    const float* __restrict__ bias,
    const float* __restrict__ uss,   // f32 [b][3072][1024], n = b*1024 + t
    int relu,
    long pstride)                    // f32-element stride between split partials (may be negative)
{
    constexpr int BM = 128, BK = 64;
    constexpr int MI = (BN == 128) ? 4 : 2;
    constexpr int NI = 4;
    const int n0 = blockIdx.x * BN, m0 = blockIdx.y * BM;
    const int Ks = K / SPLIT;
    const int kbeg = blockIdx.z * Ks;
    __shared__ __align__(16) u16 As[BM * BK];
    __shared__ __align__(16) u16 Bs[BN * BK];
    const int tid = threadIdx.x, lane = tid & 63, wv = tid >> 6;
    const int l15 = lane & 15, quad = lane >> 4;
    const int wm = (BN == 128) ? (wv >> 1) * 64 : wv * 32;
    const int wn = (BN == 128) ? (wv & 1) * 64 : 0;
    f4v acc[MI][NI] = {};
    for (int kk = kbeg; kk < kbeg + Ks; kk += BK) {
        __syncthreads();
#pragma unroll
        for (int p = 0; p < (BM * 8) / 256; ++p) {
            int c = p * 256 + tid, r = c >> 3, q = c & 7, qs = q ^ (r & 7);
            gl2lds16(&A[(size_t)(m0 + r) * K + kk + qs * 8], &As[c * 8]);
        }
#pragma unroll
        for (int p = 0; p < (BN * 8) / 256; ++p) {
            int c = p * 256 + tid, r = c >> 3, q = c & 7, qs = q ^ (r & 7);
            gl2lds16(&B[(size_t)(n0 + r) * K + kk + qs * 8], &Bs[c * 8]);
        }
        __syncthreads();
#pragma unroll
        for (int k0 = 0; k0 < BK; k0 += 32) {
            s8v af[MI], bf[NI];
#pragma unroll
            for (int mi = 0; mi < MI; ++mi) {
                int r = wm + mi * 16 + l15;
                af[mi] = *(const s8v*)&As[r * BK + ((((k0 >> 3) + quad) ^ (r & 7)) << 3)];
            }
#pragma unroll
            for (int ni = 0; ni < NI; ++ni) {
                int r = wn + ni * 16 + l15;
                bf[ni] = *(const s8v*)&Bs[r * BK + ((((k0 >> 3) + quad) ^ (r & 7)) << 3)];
            }
#pragma unroll
            for (int mi = 0; mi < MI; ++mi)
#pragma unroll
                for (int ni = 0; ni < NI; ++ni)
                    acc[mi][ni] = __builtin_amdgcn_mfma_f32_16x16x32_bf16(af[mi], bf[ni], acc[mi][ni], 0, 0, 0);
        }
    }
    if (SPLIT > 1) {
        float* base = fOut + (long)blockIdx.z * pstride;
#pragma unroll
        for (int mi = 0; mi < MI; ++mi) {
            int m = m0 + wm + mi * 16 + quad * 4;
#pragma unroll
            for (int ni = 0; ni < NI; ++ni) {
                int n = n0 + wn + ni * 16 + l15;
                *(f4v*)&base[(size_t)n * M + m] = acc[mi][ni];   // plain 16B store, no RMW
            }
        }
    } else {
#pragma unroll
        for (int mi = 0; mi < MI; ++mi) {
            int m = m0 + wm + mi * 16 + quad * 4;
            float bv[4] = {0.f, 0.f, 0.f, 0.f};
            if (bias) {
#pragma unroll
                for (int r2 = 0; r2 < 4; ++r2) bv[r2] = bias[m + r2];
            }
#pragma unroll
            for (int ni = 0; ni < NI; ++ni) {
                int n = n0 + wn + ni * 16 + l15;
                float o[4];
#pragma unroll
                for (int r2 = 0; r2 < 4; ++r2) o[r2] = acc[mi][ni][r2] + bv[r2];
                if (uss) {
                    int b = n >> 10, t = n & 1023;
#pragma unroll
                    for (int r2 = 0; r2 < 4; ++r2)
                        o[r2] += uss[((size_t)b * 3072 + m + r2) * 1024 + t];
                }
                if (relu) {
#pragma unroll
                    for (int r2 = 0; r2 < 4; ++r2) o[r2] = fmaxf(o[r2], 0.f);
                }
                s4v st;
#pragma unroll
                for (int r2 = 0; r2 < 4; ++r2) st[r2] = (short)f2s(o[r2]);
                *(s4v*)&C[(size_t)n * M + m] = st;
            }
        }
    }
}

// ---- MFMA banded flash attention ----
// block = (qtile of 16, head n, batch b); 256 thr = 4 waves.
// Keys for tile: j = j0 .. j0+271 (j0 = i0+257), c = j - j0; band: c - qi in [0,255].
// BD handled by scattering RQ[qi][t'] into S[qi][qi+t'] over an S pre-init of -1e30.
#define QT 16
#define KT 272    // 17 tiles of 16
#define KROW 72   // K LDS row stride (u16): 2-way banks
#define VROW 280  // V^T LDS row stride (u16): 2-way banks
#define SROW 272  // S row stride (f32)
#define PROW 280  // P row stride (u16)
__global__ __launch_bounds__(256) void attn_mfma(
    const u16* __restrict__ WHT,      // (BSZ, KLEN, 3*DM) bf16
    const u16* __restrict__ RT,       // (WIN, DM) bf16
    const float* __restrict__ rwb, const float* __restrict__ rrb,
    u16* __restrict__ avT)            // (BSZ, QLEN, DM) bf16
{
    __shared__ __align__(16) u16  sKV[KT * KROW];   // 39168 B; phase2 holds V^T [64][VROW]
    __shared__ __align__(16) float sS[QT * SROW];   // 17408 B
    __shared__ __align__(16) u16  sP[QT * PROW];    //  8960 B   (total = 65536 B exactly)

    const int qt = blockIdx.x, n = blockIdx.y, b = blockIdx.z;
    const int i0 = qt * QT, j0 = i0 + WIN + 1;
    const int tid = threadIdx.x, lane = tid & 63, wv = tid >> 6;
    const int l15 = lane & 15, quad = lane >> 4;
    const u16* W = WHT + (size_t)b * KLEN * (3 * DM);

    // Q fragments (A-operand rows = l15 = qi), biases baked in
    s8v qac[2], qbd[2];
    {
        int qrow = MLEN + i0 + l15;
#pragma unroll
        for (int kc = 0; kc < 2; ++kc) {
            int col = n * DH + kc * 32 + quad * 8;
            s8v qv = *(const s8v*)&W[(size_t)qrow * (3 * DM) + col];
            s8v a, c;
#pragma unroll
            for (int e = 0; e < 8; ++e) {
                float qf = s2f((u16)qv[e]);
                a[e] = (short)f2s(qf + rwb[col + e]);
                c[e] = (short)f2s(qf + rrb[col + e]);
            }
            qac[kc] = a; qbd[kc] = c;
        }
    }

    // stage K tile: row c, 8 chunks of 8 u16; j clamped (garbage lands only in masked cells)
    for (int t = tid; t < KT * 8; t += 256) {
        int r = t >> 3, q = t & 7;
        int j = j0 + r; if (j > KLEN - 1) j = KLEN - 1;
        *(s8v*)&sKV[r * KROW + q * 8] = *(const s8v*)&W[(size_t)j * (3 * DM) + DM + n * DH + q * 8];
    }
    // init S to -1e30 (mask default)
    for (int t = tid; t < QT * SROW; t += 256) sS[t] = -1e30f;
    __syncthreads();

    // RQ = rr_q @ R^T, scattered into S at [qi][qi + t']  (4 ci' tiles per wave)
#pragma unroll
    for (int cc = 0; cc < 4; ++cc) {
        int ci = wv + cc * 4;
        f4v acc = {};
#pragma unroll
        for (int kc = 0; kc < 2; ++kc) {
            s8v bf = *(const s8v*)&RT[(size_t)(ci * 16 + l15) * DM + n * DH + kc * 32 + quad * 8];
            acc = __builtin_amdgcn_mfma_f32_16x16x32_bf16(qbd[kc], bf, acc, 0, 0, 0);
        }
#pragma unroll
        for (int r2 = 0; r2 < 4; ++r2) {
            int qi = quad * 4 + r2;
            sS[qi * SROW + qi + ci * 16 + l15] = acc[r2];
        }
    }
    __syncthreads();

    // S += Q·K^T  (ci tiles round-robin over waves)
    for (int ci = wv; ci < 17; ci += 4) {
        f4v acc = {};
#pragma unroll
        for (int kc = 0; kc < 2; ++kc) {
            s8v bf = *(const s8v*)&sKV[(ci * 16 + l15) * KROW + kc * 32 + quad * 8];
            acc = __builtin_amdgcn_mfma_f32_16x16x32_bf16(qac[kc], bf, acc, 0, 0, 0);
        }
#pragma unroll
        for (int r2 = 0; r2 < 4; ++r2) {
            int qi = quad * 4 + r2;
            sS[qi * SROW + ci * 16 + l15] += acc[r2];
        }
    }
    __syncthreads();

    // stage V^T into sKV as [d][VROW]: thread group q=tid>>5 owns d-chunk, r fast for bank spread
    {
        int q = tid >> 5, r0 = tid & 31;
        for (int k = 0; k < 9; ++k) {
            int r = r0 + 32 * k;
            if (r < KT) {
                int j = j0 + r; if (j > KLEN - 1) j = KLEN - 1;
                s8v vv = *(const s8v*)&W[(size_t)j * (3 * DM) + 2 * DM + n * DH + q * 8];
#pragma unroll
                for (int e = 0; e < 8; ++e)
                    sKV[(q * 8 + e) * VROW + r] = (u16)vv[e];
            }
        }
    }

    // softmax: 16 groups of 16 lanes, group g owns row g
    {
        int g = tid >> 4, l = tid & 15;
        float vals[17], mx = -1e30f;
#pragma unroll
        for (int k = 0; k < 17; ++k) {
            float s = sS[g * SROW + l + 16 * k] * 0.125f;
            vals[k] = s; mx = fmaxf(mx, s);
        }
#pragma unroll
        for (int d = 1; d < 16; d <<= 1) mx = fmaxf(mx, __shfl_xor(mx, d, 16));
        float sum = 0.f;
#pragma unroll
        for (int k = 0; k < 17; ++k) { vals[k] = __expf(vals[k] - mx); sum += vals[k]; }
#pragma unroll
        for (int d = 1; d < 16; d <<= 1) sum += __shfl_xor(sum, d, 16);
        float inv = 1.f / sum;
#pragma unroll
        for (int k = 0; k < 17; ++k) sP[g * PROW + l + 16 * k] = f2s(vals[k] * inv);
    }
    __syncthreads();

    // O = P @ V : wave wv owns d-tile ni=wv; k = 272 -> 8 full chunks + 16-wide tail
    f4v o = {};
    for (int kc = 0; kc < 9; ++kc) {
        s8v a = {}, bb = {};
        if (kc < 8) {
            a  = *(const s8v*)&sP[l15 * PROW + kc * 32 + quad * 8];
            bb = *(const s8v*)&sKV[(wv * 16 + l15) * VROW + kc * 32 + quad * 8];
        } else if (quad < 2) {
            a  = *(const s8v*)&sP[l15 * PROW + 256 + quad * 8];
            bb = *(const s8v*)&sKV[(wv * 16 + l15) * VROW + 256 + quad * 8];
        }
        o = __builtin_amdgcn_mfma_f32_16x16x32_bf16(a, bb, o, 0, 0, 0);
    }
#pragma unroll
    for (int r2 = 0; r2 < 4; ++r2) {
        int qi = quad * 4 + r2;
        avT[((size_t)b * QLEN + i0 + qi) * DM + n * DH + wv * 16 + l15] = f2s(o[r2]);
    }
}

// ---- layernorm: out = LN(sum of nparts partials + bias + res_bf16), row-contiguous ----
__global__ __launch_bounds__(256) void ln_f(
    const float* __restrict__ P, long pstride, int nparts,
    const float* __restrict__ bias,
    const u16* __restrict__ res, int resMode, u16* __restrict__ out)
{
    int n = blockIdx.x, tid = threadIdx.x;
    int lane = tid & 63, wv = tid >> 6;
    int f = tid * 4;
    int rrow = resMode ? (((n >> 9) * 2 + 1) * 512 + (n & 511)) : n;
    f4v pv = *(const f4v*)&P[(size_t)n * DM + f];
    for (int p = 1; p < nparts; ++p) {
        const float* Pp = P + (long)p * pstride;
        pv += *(const f4v*)&Pp[(size_t)n * DM + f];
    }
    s4v rv = *(const s4v*)&res[(size_t)rrow * DM + f];
    f4v bv = *(const f4v*)&bias[f];
    float v[4];
#pragma unroll
    for (int k = 0; k < 4; ++k) v[k] = pv[k] + bv[k] + s2f((u16)rv[k]);
    float s = v[0] + v[1] + v[2] + v[3];
    float ss = v[0] * v[0] + v[1] * v[1] + v[2] * v[2] + v[3] * v[3];
#pragma unroll
    for (int d = 1; d < 64; d <<= 1) {
        s += __shfl_xor(s, d, 64);
        ss += __shfl_xor(ss, d, 64);
    }
    __shared__ float ps[4], pss[4];
    if (lane == 0) { ps[wv] = s; pss[wv] = ss; }
    __syncthreads();
    float S = ps[0] + ps[1] + ps[2] + ps[3];
    float SS = pss[0] + pss[1] + pss[2] + pss[3];
    float m = S * (1.f / DM);
    float var = SS * (1.f / DM) - m * m;
    float inv = rsqrtf(fmaxf(var, 0.f) + 1e-5f);
    s4v st;
#pragma unroll
    for (int k = 0; k < 4; ++k) st[k] = (short)f2s((v[k] - m) * inv);
    *(s4v*)&out[(size_t)n * DM + f] = st;
}

extern "C" void kernel_launch(void* const* d_in, const int* in_sizes, int n_in,
                              void* d_out, int out_size, void* d_ws, size_t ws_size,
                              hipStream_t stream) {
    const float* z1ss  = (const float*)d_in[0];
    const float* uss   = (const float*)d_in[1];
    const float* z0    = (const float*)d_in[2];
    const float* pos   = (const float*)d_in[3];
    const float* qkv_w = (const float*)d_in[4];
    const float* r_w   = (const float*)d_in[5];
    const float* rwb   = (const float*)d_in[6];
    const float* rrb   = (const float*)d_in[7];
    const float* o_w   = (const float*)d_in[8];
    const float* o_b   = (const float*)d_in[9];
    const float* ff1_w = (const float*)d_in[10];
    const float* ff1_b = (const float*)d_in[11];
    const float* ff2_w = (const float*)d_in[12];
    const float* ff2_b = (const float*)d_in[13];

    u16* ws = (u16*)d_ws;
    u16* wQ   = ws;             // 3072x1024
    u16* wR   = ws + 3145728;
    u16* wO   = ws + 4194304;
    u16* wF1  = ws + 5242880;
    u16* wF2  = ws + 9437184;
    u16* catT = ws + 13631488;  // (4,1024,1024); later aliased as outT
    u16* whT  = ws + 17825792;  // (4,1024,3072); later aliased as hT
    u16* posT = ws + 30408704;  // (256,1024)
    u16* rT   = ws + 30670848;  // (256,1024)
    u16* avT  = ws + 30932992;  // (2048,1024)
    u16* xT   = ws + 33030144;  // (2048,1024)
    float* pref = (float*)(ws + 35127296);  // 2048x1024 f32  (split partial 0)
    u16* hT   = whT;
    u16* outT = catT;

    // split partial 1: workspace offset 0 = wQ+wR region (exactly 8 MB), dead by the
    // time o-proj / ff2 run (qkv + r gemms already consumed those weights).
    float* part1 = (float*)d_ws;
    long pstr = part1 - pref;   // negative f32-element stride between partials

    dim3 tblk(32, 8);

    conv_w5<<<13312, 256, 0, stream>>>(qkv_w, r_w, o_w, ff1_w, ff2_w,
                                       wQ, wR, wO, wF1, wF2);

    trans_f2b<<<dim3(16, 32, BSZ), tblk, 0, stream>>>(z0, (long)DM * MLEN, MLEN, 0,
                                                      catT, (long)KLEN * DM, DM, 0);
    trans_f2b<<<dim3(16, 32, BSZ), tblk, 0, stream>>>(z1ss, (long)DM * QLEN, QLEN, 0,
                                                      catT, (long)KLEN * DM, DM, MLEN);
    trans_f2b<<<dim3(8, 32, 1), tblk, 0, stream>>>(pos, 0, KLEN, KLEN - WIN,
                                                   posT, 0, DM, 0);

    // qkv: whT(4096 x 3072) = (qkv_w @ cat)^T   (uss added by trans_add below)
    // BN=64: grid 1536 blocks -> 6 blocks/CU (24 KB LDS), vs 3/CU at BN=128
    gemm_bt<64, 1><<<dim3(64, 24, 1), 256, 0, stream>>>(
        wQ, catT, whT, nullptr, 3 * DM, DM, nullptr, nullptr, 0, 0);

    // whT += uss^T  (coalesced transpose-add; removes 64 stride-4KB scalar loads
    // per thread from the qkv epilogue)
    trans_add<<<dim3(32, 96, BSZ), tblk, 0, stream>>>(uss, whT);

    // r: rT(256 x 1024) = (r_w @ pos[:,768:])^T
    gemm_bt<64, 1><<<dim3(4, 8, 1), 256, 0, stream>>>(
        wR, posT, rT, nullptr, DM, DM, nullptr, nullptr, 0, 0);

    // MFMA banded attention -> avT
    attn_mfma<<<dim3(QLEN / QT, NH, BSZ), 256, 0, stream>>>(whT, rT, rwb, rrb, avT);

    // o-proj split-2, private partials (no atomics, no memset)
    gemm_bt<64, 2><<<dim3(32, 8, 2), 256, 0, stream>>>(
        wO, avT, nullptr, pref, DM, DM, nullptr, nullptr, 0, pstr);

    ln_f<<<2048, 256, 0, stream>>>(pref, pstr, 2, o_b, catT, 1, xT);

    // ff1  (BN=64: grid 1024 blocks -> 4+ blocks/CU, was 512 = 2/CU)
    gemm_bt<64, 1><<<dim3(32, 32, 1), 256, 0, stream>>>(
        wF1, xT, hT, nullptr, DI, DM, ff1_b, nullptr, 1, 0);

    // ff2 split-2, private partials (no atomics, no memset)
    gemm_bt<64, 2><<<dim3(32, 8, 2), 256, 0, stream>>>(
        wF2, hT, nullptr, pref, DM, DI, nullptr, nullptr, 0, pstr);

    ln_f<<<2048, 256, 0, stream>>>(pref, pstr, 2, ff2_b, xT, 0, outT);

    trans_b2f<<<dim3(32, 16, BSZ), tblk, 0, stream>>>(outT, (long)QLEN * DM, DM,
                                                      (float*)d_out, (long)DM * QLEN, QLEN);
}

// Round 3
// 344.942 us; speedup vs baseline: 1.4636x; 1.0585x over previous
//
#include <hip/hip_runtime.h>
#include <hip/hip_bf16.h>

typedef unsigned short u16;
typedef __attribute__((ext_vector_type(8))) short s8v;
typedef __attribute__((ext_vector_type(4))) short s4v;
typedef __attribute__((ext_vector_type(4))) float f4v;

__device__ __forceinline__ float s2f(u16 s) {
    unsigned int u = ((unsigned int)s) << 16;
    return __builtin_bit_cast(float, u);
}
__device__ __forceinline__ u16 f2s(float f) {
    __hip_bfloat16 h = __float2bfloat16(f);
    return __builtin_bit_cast(u16, h);
}

// async global->LDS DMA, 16 B per lane; LDS dst must be lane-linear
__device__ __forceinline__ void gl2lds16(const u16* g, u16* l) {
    __builtin_amdgcn_global_load_lds((const __attribute__((address_space(1))) void*)g,
                                     (__attribute__((address_space(3))) void*)l, 16, 0, 0);
}

#define BSZ 4
#define DM 1024
#define QLEN 512
#define MLEN 512
#define KLEN 1024
#define DI 4096
#define NH 16
#define DH 64
#define WIN 256   // valid keys: j = i+257 .. i+512 (exactly 256 per query, never clipped)

// ---- merged f32 -> bf16 weight conversion (5 tensors, 1 launch) ----
__global__ __launch_bounds__(256) void conv_w5(
    const float* __restrict__ s0, const float* __restrict__ s1,
    const float* __restrict__ s2, const float* __restrict__ s3,
    const float* __restrict__ s4,
    u16* __restrict__ d0, u16* __restrict__ d1, u16* __restrict__ d2,
    u16* __restrict__ d3, u16* __restrict__ d4)
{
    const int e0 = 786432, e1 = e0 + 262144, e2 = e1 + 262144,
              e3 = e2 + 1048576, e4 = e3 + 1048576;
    int i = blockIdx.x * 256 + threadIdx.x;
    const float* s; u16* d; int off;
    if (i < e0)      { s = s0; d = d0; off = i; }
    else if (i < e1) { s = s1; d = d1; off = i - e0; }
    else if (i < e2) { s = s2; d = d2; off = i - e1; }
    else if (i < e3) { s = s3; d = d3; off = i - e2; }
    else if (i < e4) { s = s4; d = d4; off = i - e3; }
    else return;
    f4v v = *(const f4v*)&s[(size_t)off * 4];
    s4v o;
#pragma unroll
    for (int k = 0; k < 4; ++k) o[k] = (short)f2s(v[k]);
    *(s4v*)&d[(size_t)off * 4] = o;
}

// ---- transpose f32 (feature-major) -> bf16 (position-major) ----
__global__ __launch_bounds__(256) void trans_f2b(
    const float* __restrict__ src, long sS, int ldS, int colOff,
    u16* __restrict__ dst, long sD, int ldD, int rowOff)
{
    __shared__ float tile[32][33];
    int b = blockIdx.z;
    int t0 = blockIdx.x * 32, f0 = blockIdx.y * 32;
    int tx = threadIdx.x, ty = threadIdx.y;   // (32, 8)
#pragma unroll
    for (int p = 0; p < 4; ++p)
        tile[ty + 8 * p][tx] = src[(size_t)b * sS + (size_t)(f0 + ty + 8 * p) * ldS + colOff + t0 + tx];
    __syncthreads();
#pragma unroll
    for (int p = 0; p < 4; ++p)
        dst[(size_t)b * sD + (size_t)(rowOff + t0 + ty + 8 * p) * ldD + f0 + tx] = f2s(tile[tx][ty + 8 * p]);
}

// ---- transpose-add: dst(bf16, [b][1024][3072]) += src(f32, [b][3072][1024])^T ----
// (covers only the Q,K thirds now: f0 < 2048; V third is handled in the gemm epilogue)
__global__ __launch_bounds__(256) void trans_add(
    const float* __restrict__ src, u16* __restrict__ dst)
{
    __shared__ float tile[32][33];
    int b = blockIdx.z;
    int t0 = blockIdx.x * 32, f0 = blockIdx.y * 32;
    int tx = threadIdx.x, ty = threadIdx.y;   // (32, 8)
    const float* S = src + (size_t)b * 3072 * 1024;
    u16* D = dst + (size_t)b * 1024 * 3072;
#pragma unroll
    for (int p = 0; p < 4; ++p)
        tile[ty + 8 * p][tx] = S[(size_t)(f0 + ty + 8 * p) * 1024 + t0 + tx];
    __syncthreads();
#pragma unroll
    for (int p = 0; p < 4; ++p) {
        size_t o = (size_t)(t0 + ty + 8 * p) * 3072 + f0 + tx;
        D[o] = f2s(s2f(D[o]) + tile[tx][ty + 8 * p]);
    }
}

// ---- transpose bf16 (position-major) -> f32 (feature-major) ----
__global__ __launch_bounds__(256) void trans_b2f(
    const u16* __restrict__ src, long sS, int ldS,
    float* __restrict__ dst, long sD, int ldD)
{
    __shared__ float tile[32][33];
    int b = blockIdx.z;
    int t0 = blockIdx.x * 32, f0 = blockIdx.y * 32;
    int tx = threadIdx.x, ty = threadIdx.y;
#pragma unroll
    for (int p = 0; p < 4; ++p)
        tile[ty + 8 * p][tx] = s2f(src[(size_t)b * sS + (size_t)(f0 + ty + 8 * p) * ldS + t0 + tx]);
    __syncthreads();
#pragma unroll
    for (int p = 0; p < 4; ++p)
        dst[(size_t)b * sD + (size_t)(t0 + ty + 8 * p) * ldD + f0 + tx] = tile[tx][ty + 8 * p];
}

// ---- MFMA GEMM (m97-style): C^T(N x M) = A(M x K, bf16) @ B^T(N x K, bf16) ----
// SPLIT>1: each z writes a PRIVATE f32 partial buffer at fOut + z*pstride (no atomics).
// vTout: for m0 >= 2048 (qkv V-third), write transposed to vTout[m-2048][n] with uss
//        V-third added (ussV is feature-major like vT -> coalesced loads).
template<int BN, int SPLIT>
__global__ __launch_bounds__(256) void gemm_bt(
    const u16* __restrict__ A,
    const u16* __restrict__ B,
    u16* __restrict__ C,
    float* __restrict__ fOut,
    int M, int K,
    const float* __restrict__ bias,
    int relu,
    long pstride,
    const float* __restrict__ ussV,
    u16* __restrict__ vTout)
{
    constexpr int BM = 128, BK = 64;
    constexpr int MI = (BN == 128) ? 4 : 2;
    constexpr int NI = 4;
    const int n0 = blockIdx.x * BN, m0 = blockIdx.y * BM;
    const int Ks = K / SPLIT;
    const int kbeg = blockIdx.z * Ks;
    __shared__ __align__(16) u16 As[BM * BK];
    __shared__ __align__(16) u16 Bs[BN * BK];
    const int tid = threadIdx.x, lane = tid & 63, wv = tid >> 6;
    const int l15 = lane & 15, quad = lane >> 4;
    const int wm = (BN == 128) ? (wv >> 1) * 64 : wv * 32;
    const int wn = (BN == 128) ? (wv & 1) * 64 : 0;
    f4v acc[MI][NI] = {};
    for (int kk = kbeg; kk < kbeg + Ks; kk += BK) {
        __syncthreads();
#pragma unroll
        for (int p = 0; p < (BM * 8) / 256; ++p) {
            int c = p * 256 + tid, r = c >> 3, q = c & 7, qs = q ^ (r & 7);
            gl2lds16(&A[(size_t)(m0 + r) * K + kk + qs * 8], &As[c * 8]);
        }
#pragma unroll
        for (int p = 0; p < (BN * 8) / 256; ++p) {
            int c = p * 256 + tid, r = c >> 3, q = c & 7, qs = q ^ (r & 7);
            gl2lds16(&B[(size_t)(n0 + r) * K + kk + qs * 8], &Bs[c * 8]);
        }
        __syncthreads();
#pragma unroll
        for (int k0 = 0; k0 < BK; k0 += 32) {
            s8v af[MI], bf[NI];
#pragma unroll
            for (int mi = 0; mi < MI; ++mi) {
                int r = wm + mi * 16 + l15;
                af[mi] = *(const s8v*)&As[r * BK + ((((k0 >> 3) + quad) ^ (r & 7)) << 3)];
            }
#pragma unroll
            for (int ni = 0; ni < NI; ++ni) {
                int r = wn + ni * 16 + l15;
                bf[ni] = *(const s8v*)&Bs[r * BK + ((((k0 >> 3) + quad) ^ (r & 7)) << 3)];
            }
#pragma unroll
            for (int mi = 0; mi < MI; ++mi)
#pragma unroll
                for (int ni = 0; ni < NI; ++ni)
                    acc[mi][ni] = __builtin_amdgcn_mfma_f32_16x16x32_bf16(af[mi], bf[ni], acc[mi][ni], 0, 0, 0);
        }
    }
    if (SPLIT > 1) {
        float* base = fOut + (long)blockIdx.z * pstride;
#pragma unroll
        for (int mi = 0; mi < MI; ++mi) {
            int m = m0 + wm + mi * 16 + quad * 4;
#pragma unroll
            for (int ni = 0; ni < NI; ++ni) {
                int n = n0 + wn + ni * 16 + l15;
                *(f4v*)&base[(size_t)n * M + m] = acc[mi][ni];   // plain 16B store, no RMW
            }
        }
    } else if (vTout && m0 >= 2048) {
        // V third of qkv: write V^T[d][n] (+ uss V-third, coalesced in this layout)
#pragma unroll
        for (int mi = 0; mi < MI; ++mi) {
            int m = m0 + wm + mi * 16 + quad * 4;
#pragma unroll
            for (int ni = 0; ni < NI; ++ni) {
                int n = n0 + wn + ni * 16 + l15;
                int b = n >> 10, t = n & 1023;
#pragma unroll
                for (int r2 = 0; r2 < 4; ++r2) {
                    float o = acc[mi][ni][r2] + ussV[((size_t)b * 3072 + (m + r2)) * 1024 + t];
                    vTout[(size_t)(m + r2 - 2048) * 4096 + n] = f2s(o);
                }
            }
        }
    } else {
#pragma unroll
        for (int mi = 0; mi < MI; ++mi) {
            int m = m0 + wm + mi * 16 + quad * 4;
            float bv[4] = {0.f, 0.f, 0.f, 0.f};
            if (bias) {
#pragma unroll
                for (int r2 = 0; r2 < 4; ++r2) bv[r2] = bias[m + r2];
            }
#pragma unroll
            for (int ni = 0; ni < NI; ++ni) {
                int n = n0 + wn + ni * 16 + l15;
                float o[4];
#pragma unroll
                for (int r2 = 0; r2 < 4; ++r2) o[r2] = acc[mi][ni][r2] + bv[r2];
                if (relu) {
#pragma unroll
                    for (int r2 = 0; r2 < 4; ++r2) o[r2] = fmaxf(o[r2], 0.f);
                }
                s4v st;
#pragma unroll
                for (int r2 = 0; r2 < 4; ++r2) st[r2] = (short)f2s(o[r2]);
                *(s4v*)&C[(size_t)n * M + m] = st;
            }
        }
    }
}

// ---- MFMA banded flash attention (v2: direct-global K/V, LDS = S only) ----
// Band is EXACTLY 256 keys/query: j = i + 257 .. i + 512 (never clipped by klen).
// Shifted S: S[qi][t], t = j - (j0 + qi), t in [0,256). No masking, no -1e30 init.
// K fragments read direct global (one 128B line per row, fully consumed; zero reuse).
// V fragments read direct global from vT (feature-major V^T produced by qkv gemm).
// P aliased in-place over S rows (u16), padded to 288 k-cols with exact zeros -> 9 clean chunks.
#define QT 16
#define SROW 260   // f32 row stride: 260 % 32 == 4 -> 2-way banks on row-indexed reads
__global__ __launch_bounds__(256, 4) void attn_mfma(
    const u16* __restrict__ WHT,      // (BSZ, KLEN, 3*DM) bf16 (Q,K thirds valid)
    const u16* __restrict__ VT,       // (DM, BSZ*KLEN) bf16 = V^T (+uss), cols n=b*1024+t
    const u16* __restrict__ RT,       // (WIN, DM) bf16
    const float* __restrict__ rwb, const float* __restrict__ rrb,
    u16* __restrict__ avT)            // (BSZ, QLEN, DM) bf16
{
    __shared__ __align__(16) float sS[QT * SROW];   // 16640 B total LDS

    const int qt = blockIdx.x, n = blockIdx.y, b = blockIdx.z;
    const int i0 = qt * QT, j0 = i0 + WIN + 1;
    const int tid = threadIdx.x, lane = tid & 63, wv = tid >> 6;
    const int l15 = lane & 15, quad = lane >> 4;
    const u16* W = WHT + (size_t)b * KLEN * (3 * DM);

    // Q fragments (A-operand rows = l15 = qi), biases baked in
    s8v qac[2], qbd[2];
    {
        int qrow = MLEN + i0 + l15;
#pragma unroll
        for (int kc = 0; kc < 2; ++kc) {
            int col = n * DH + kc * 32 + quad * 8;
            s8v qv = *(const s8v*)&W[(size_t)qrow * (3 * DM) + col];
            s8v a, c;
#pragma unroll
            for (int e = 0; e < 8; ++e) {
                float qf = s2f((u16)qv[e]);
                a[e] = (short)f2s(qf + rwb[col + e]);
                c[e] = (short)f2s(qf + rrb[col + e]);
            }
            qac[kc] = a; qbd[kc] = c;
        }
    }

    // Phase 1: S[qi][t] = AC (QK^T), K direct from global, shifted predicated store
    for (int ci = wv; ci < 17; ci += 4) {
        f4v acc = {};
        const u16* Kr = &W[(size_t)(j0 + ci * 16 + l15) * (3 * DM) + DM + n * DH + quad * 8];
        acc = __builtin_amdgcn_mfma_f32_16x16x32_bf16(qac[0], *(const s8v*)Kr, acc, 0, 0, 0);
        acc = __builtin_amdgcn_mfma_f32_16x16x32_bf16(qac[1], *(const s8v*)(Kr + 32), acc, 0, 0, 0);
#pragma unroll
        for (int r2 = 0; r2 < 4; ++r2) {
            int qi = quad * 4 + r2;
            int t = ci * 16 + l15 - qi;
            if ((unsigned)t < 256u) sS[qi * SROW + t] = acc[r2];
        }
    }
    __syncthreads();

    // Phase 2: S[qi][t'] += BD (rr_q @ R^T), R direct from global, unshifted in t'
#pragma unroll
    for (int cc = 0; cc < 4; ++cc) {
        int ci = wv + cc * 4;
        f4v acc = {};
        const u16* Rr = &RT[(size_t)(ci * 16 + l15) * DM + n * DH + quad * 8];
        acc = __builtin_amdgcn_mfma_f32_16x16x32_bf16(qbd[0], *(const s8v*)Rr, acc, 0, 0, 0);
        acc = __builtin_amdgcn_mfma_f32_16x16x32_bf16(qbd[1], *(const s8v*)(Rr + 32), acc, 0, 0, 0);
#pragma unroll
        for (int r2 = 0; r2 < 4; ++r2) {
            int qi = quad * 4 + r2;
            sS[qi * SROW + ci * 16 + l15] += acc[r2];
        }
    }
    __syncthreads();

    // Phase 3: softmax row g over t in [0,256); write P (bf16) in-place over S row g at
    // c' = qi + 1 + t (so P k-index c' matches V col (j0-1)+c'); zero-pad c' in [0,qi] and
    // [qi+257, 288). 16-lane groups are wave-lockstep: all reads complete before writes.
    {
        int g = tid >> 4, l = tid & 15;
        float vals[16], mx = -1e30f;
#pragma unroll
        for (int k = 0; k < 16; ++k) {
            float s = sS[g * SROW + l + 16 * k] * 0.125f;
            vals[k] = s; mx = fmaxf(mx, s);
        }
        asm volatile("" ::: "memory");   // fence: S f32 reads before u16 P writes (aliased)
#pragma unroll
        for (int d = 1; d < 16; d <<= 1) mx = fmaxf(mx, __shfl_xor(mx, d, 16));
        float sum = 0.f;
#pragma unroll
        for (int k = 0; k < 16; ++k) { vals[k] = __expf(vals[k] - mx); sum += vals[k]; }
#pragma unroll
        for (int d = 1; d < 16; d <<= 1) sum += __shfl_xor(sum, d, 16);
        float inv = 1.f / sum;
        u16* sPr = (u16*)&sS[g * SROW];
#pragma unroll
        for (int k = 0; k < 16; ++k) sPr[g + 1 + l + 16 * k] = f2s(vals[k] * inv);
        sPr[l <= g ? l : 256 + l] = 0;   // zeros [0,g] and [g+257,272)
        sPr[272 + l] = 0;                // zeros [272,288)
    }
    __syncthreads();

    // Phase 4: O = P @ V, V^T fragments direct from global; 9 clean k-chunks of 32
    const u16* sPu = (const u16*)sS;
    const size_t vbase = (size_t)(n * DH + wv * 16 + l15) * 4096
                       + (size_t)b * KLEN + (j0 - 1) + quad * 8;
    f4v o = {};
#pragma unroll
    for (int kc = 0; kc < 9; ++kc) {
        size_t vi = vbase + kc * 32;
        if (vi > (size_t)4194304 - 8) vi = (size_t)4194304 - 8;  // clamp (P=0 there)
        s8v a  = *(const s8v*)&sPu[(size_t)l15 * (2 * SROW) + kc * 32 + quad * 8];
        s8v bb = *(const s8v*)&VT[vi];
        o = __builtin_amdgcn_mfma_f32_16x16x32_bf16(a, bb, o, 0, 0, 0);
    }
#pragma unroll
    for (int r2 = 0; r2 < 4; ++r2) {
        int qi = quad * 4 + r2;
        avT[((size_t)b * QLEN + i0 + qi) * DM + n * DH + wv * 16 + l15] = f2s(o[r2]);
    }
}

// ---- layernorm: out = LN(sum of nparts partials + bias + res_bf16), row-contiguous ----
__global__ __launch_bounds__(256) void ln_f(
    const float* __restrict__ P, long pstride, int nparts,
    const float* __restrict__ bias,
    const u16* __restrict__ res, int resMode, u16* __restrict__ out)
{
    int n = blockIdx.x, tid = threadIdx.x;
    int lane = tid & 63, wv = tid >> 6;
    int f = tid * 4;
    int rrow = resMode ? (((n >> 9) * 2 + 1) * 512 + (n & 511)) : n;
    f4v pv = *(const f4v*)&P[(size_t)n * DM + f];
    for (int p = 1; p < nparts; ++p) {
        const float* Pp = P + (long)p * pstride;
        pv += *(const f4v*)&Pp[(size_t)n * DM + f];
    }
    s4v rv = *(const s4v*)&res[(size_t)rrow * DM + f];
    f4v bv = *(const f4v*)&bias[f];
    float v[4];
#pragma unroll
    for (int k = 0; k < 4; ++k) v[k] = pv[k] + bv[k] + s2f((u16)rv[k]);
    float s = v[0] + v[1] + v[2] + v[3];
    float ss = v[0] * v[0] + v[1] * v[1] + v[2] * v[2] + v[3] * v[3];
#pragma unroll
    for (int d = 1; d < 64; d <<= 1) {
        s += __shfl_xor(s, d, 64);
        ss += __shfl_xor(ss, d, 64);
    }
    __shared__ float ps[4], pss[4];
    if (lane == 0) { ps[wv] = s; pss[wv] = ss; }
    __syncthreads();
    float S = ps[0] + ps[1] + ps[2] + ps[3];
    float SS = pss[0] + pss[1] + pss[2] + pss[3];
    float m = S * (1.f / DM);
    float var = SS * (1.f / DM) - m * m;
    float inv = rsqrtf(fmaxf(var, 0.f) + 1e-5f);
    s4v st;
#pragma unroll
    for (int k = 0; k < 4; ++k) st[k] = (short)f2s((v[k] - m) * inv);
    *(s4v*)&out[(size_t)n * DM + f] = st;
}

extern "C" void kernel_launch(void* const* d_in, const int* in_sizes, int n_in,
                              void* d_out, int out_size, void* d_ws, size_t ws_size,
                              hipStream_t stream) {
    const float* z1ss  = (const float*)d_in[0];
    const float* uss   = (const float*)d_in[1];
    const float* z0    = (const float*)d_in[2];
    const float* pos   = (const float*)d_in[3];
    const float* qkv_w = (const float*)d_in[4];
    const float* r_w   = (const float*)d_in[5];
    const float* rwb   = (const float*)d_in[6];
    const float* rrb   = (const float*)d_in[7];
    const float* o_w   = (const float*)d_in[8];
    const float* o_b   = (const float*)d_in[9];
    const float* ff1_w = (const float*)d_in[10];
    const float* ff1_b = (const float*)d_in[11];
    const float* ff2_w = (const float*)d_in[12];
    const float* ff2_b = (const float*)d_in[13];

    u16* ws = (u16*)d_ws;
    u16* wQ   = ws;             // 3072x1024
    u16* wR   = ws + 3145728;
    u16* wO   = ws + 4194304;
    u16* wF1  = ws + 5242880;
    u16* wF2  = ws + 9437184;
    u16* catT = ws + 13631488;  // (4,1024,1024); later aliased as outT
    u16* whT  = ws + 17825792;  // (4,1024,3072); later aliased as hT
    u16* posT = ws + 30408704;  // (256,1024)
    u16* rT   = ws + 30670848;  // (256,1024)
    u16* avT  = ws + 30932992;  // (2048,1024)
    u16* xT   = ws + 33030144;  // (2048,1024)
    float* pref = (float*)(ws + 35127296);  // 2048x1024 f32  (split partial 0)
    u16* hT   = whT;
    u16* outT = catT;

    // vT (1024 x 4096 bf16, = 8 MB) aliases pref: live only between qkv gemm and attn;
    // pref is first written by o-proj (after attn). OOB tail reads are clamped in-kernel.
    u16* vT = (u16*)pref;

    // split partial 1: workspace offset 0 (wQ+wR region, dead once o-proj/ff2 run)
    float* part1 = (float*)d_ws;
    long pstr = part1 - pref;   // negative f32-element stride between partials

    dim3 tblk(32, 8);

    conv_w5<<<13312, 256, 0, stream>>>(qkv_w, r_w, o_w, ff1_w, ff2_w,
                                       wQ, wR, wO, wF1, wF2);

    trans_f2b<<<dim3(16, 32, BSZ), tblk, 0, stream>>>(z0, (long)DM * MLEN, MLEN, 0,
                                                      catT, (long)KLEN * DM, DM, 0);
    trans_f2b<<<dim3(16, 32, BSZ), tblk, 0, stream>>>(z1ss, (long)DM * QLEN, QLEN, 0,
                                                      catT, (long)KLEN * DM, DM, MLEN);
    trans_f2b<<<dim3(8, 32, 1), tblk, 0, stream>>>(pos, 0, KLEN, KLEN - WIN,
                                                   posT, 0, DM, 0);

    // qkv: whT(4096 x 3072) = (qkv_w @ cat)^T for Q,K thirds; V third -> vT[d][n] (+uss V)
    gemm_bt<64, 1><<<dim3(64, 24, 1), 256, 0, stream>>>(
        wQ, catT, whT, nullptr, 3 * DM, DM, nullptr, 0, 0, uss, vT);

    // whT += uss^T for Q,K thirds only
    trans_add<<<dim3(32, 64, BSZ), tblk, 0, stream>>>(uss, whT);

    // r: rT(256 x 1024) = (r_w @ pos[:,768:])^T
    gemm_bt<64, 1><<<dim3(4, 8, 1), 256, 0, stream>>>(
        wR, posT, rT, nullptr, DM, DM, nullptr, 0, 0, nullptr, nullptr);

    // MFMA banded attention -> avT  (LDS = 16.6 KB, direct-global K/V)
    attn_mfma<<<dim3(QLEN / QT, NH, BSZ), 256, 0, stream>>>(whT, vT, rT, rwb, rrb, avT);

    // o-proj split-2, private partials (overwrites pref/vT: attn already consumed vT)
    gemm_bt<64, 2><<<dim3(32, 8, 2), 256, 0, stream>>>(
        wO, avT, nullptr, pref, DM, DM, nullptr, 0, pstr, nullptr, nullptr);

    ln_f<<<2048, 256, 0, stream>>>(pref, pstr, 2, o_b, catT, 1, xT);

    // ff1
    gemm_bt<64, 1><<<dim3(32, 32, 1), 256, 0, stream>>>(
        wF1, xT, hT, nullptr, DI, DM, ff1_b, 1, 0, nullptr, nullptr);

    // ff2 split-2, private partials
    gemm_bt<64, 2><<<dim3(32, 8, 2), 256, 0, stream>>>(
        wF2, hT, nullptr, pref, DM, DI, nullptr, 0, pstr, nullptr, nullptr);

    ln_f<<<2048, 256, 0, stream>>>(pref, pstr, 2, ff2_b, xT, 0, outT);

    trans_b2f<<<dim3(32, 16, BSZ), tblk, 0, stream>>>(outT, (long)QLEN * DM, DM,
                                                      (float*)d_out, (long)DM * QLEN, QLEN);
}